// Round 4
// baseline (347.822 us; speedup 1.0000x reference)
//
#include <hip/hip_runtime.h>
#include <math.h>

#define NB 4
#define LL 4096
#define DD 1024
#define MM 256

typedef short s16x8 __attribute__((ext_vector_type(8)));
typedef short s16x4 __attribute__((ext_vector_type(4)));
typedef float fx4 __attribute__((ext_vector_type(4)));
typedef unsigned u32x2 __attribute__((ext_vector_type(2)));

__device__ __forceinline__ float b2f(short s) {
  union { unsigned u; float f; } v;
  v.u = ((unsigned)(unsigned short)s) << 16;
  return v.f;
}
__device__ __forceinline__ short f2b(float f) {
  union { float f; unsigned u; } v;
  v.f = f;
  unsigned r = (v.u + 0x7fffu + ((v.u >> 16) & 1u)) >> 16;
  return (short)(unsigned short)r;
}
// packed fp32->bf16 (RNE), 2 values per instruction
__device__ __forceinline__ unsigned cvt2(float lo, float hi) {
  unsigned r;
  asm("v_cvt_pk_bf16_f32 %0, %1, %2" : "=v"(r) : "v"(lo), "v"(hi));
  return r;
}
// 4-chunk swizzle key for 32-k-wide GLL16 tiles (2-way max on frag reads)
__device__ __forceinline__ int keyf(int m) { return (m ^ (m >> 2)) & 3; }

typedef __attribute__((address_space(1))) const void* gas1_t;
typedef __attribute__((address_space(3))) void* las3_t;
#define GLL16(g, l) __builtin_amdgcn_global_load_lds((gas1_t)(const void*)(g), (las3_t)(void*)(l), 16, 0, 0)

// ---------------- cast fp32 -> bf16 (P only) ----------------
__global__ __launch_bounds__(256) void k_cast(const float* __restrict__ in, short* __restrict__ out, int n4) {
  int i = blockIdx.x * 256 + threadIdx.x;
  if (i >= n4) return;
  float4 v = ((const float4*)in)[i];
  s16x4 s;
  s[0] = f2b(v.x); s[1] = f2b(v.y); s[2] = f2b(v.z); s[3] = f2b(v.w);
  ((s16x4*)out)[i] = s;
}

// ---------------- rf GEMM: block = [32 l] x [256 m], K staged as full-row halves ----------------
// A (X rows) read CONTIGUOUSLY (2KB per row-half), LDS-resident across 16 K-steps per half.
// z<4: rf_q (B,L,M) incl 1/sqrt(M); z>=4: rf_kT (B,M,L) + Z atomics.
__global__ __launch_bounds__(512) void k_qk(const float* __restrict__ Q, const float* __restrict__ K,
                                            const short* __restrict__ Pb,
                                            short* __restrict__ rfq, short* __restrict__ rfkT,
                                            float* __restrict__ Zz) {
  __shared__ short As[32 * 512];   // 32 KB: [32 l][512 k] swizzled (8-granule XOR by row&7)
  __shared__ short Bs[256 * 32];   // 16 KB: [256 m][4 chunks of 8], chunk ^ keyf(m)
  int z = blockIdx.z, mode = z >> 2, b = z & 3;
  int l0 = blockIdx.x * 32;
  const float* X = mode ? K : Q;
  int tid = threadIdx.x, lane = tid & 63, w = tid >> 6;

  // B staging pointers (2 slots/thread), key identical for m and m+128
  int bm = tid >> 2, bs = tid & 3;
  int bcs = bs ^ keyf(bm);
  const short* PbS0 = Pb + (size_t)bm * DD + bcs * 8;
  const short* PbS1 = Pb + (size_t)(bm + 128) * DD + bcs * 8;

  fx4 acc[2][2] = {};

  for (int h = 0; h < 2; ++h) {
    // ---- stage A half: 32 rows x 512 k, fully contiguous 2KB per row ----
    const float* Xb = X + ((size_t)b * LL + l0) * DD + h * 512;
    float4 pa[8];
    #pragma unroll
    for (int i = 0; i < 8; ++i) {
      int g = i * 512 + tid;
      pa[i] = *(const float4*)(Xb + (size_t)(g >> 7) * DD + (g & 127) * 4);
    }
    #pragma unroll
    for (int i = 0; i < 8; ++i) {
      int g = i * 512 + tid, row = g >> 7, col = (g & 127) * 4;
      int sc = (col & ~63) | ((col & 63) ^ ((row & 7) << 3));
      u32x2 vv;
      vv[0] = cvt2(pa[i].x, pa[i].y);
      vv[1] = cvt2(pa[i].z, pa[i].w);
      *(u32x2*)&As[row * 512 + sc] = vv;
    }
    __syncthreads();
    // ---- 16 K-steps of 32 over the resident half ----
    int koff = h * 512;
    for (int st = 0; st < 16; ++st) {
      int ko = koff + st * 32;
      GLL16(PbS0 + ko, &Bs[tid * 8]);
      GLL16(PbS1 + ko, &Bs[(tid + 512) * 8]);
      __syncthreads();
      int kg = lane >> 4;
      int colA = st * 32 + kg * 8;
      s16x8 af[2], bf[2];
      #pragma unroll
      for (int mi = 0; mi < 2; ++mi) {
        int row = mi * 16 + (lane & 15);
        int sc = (colA & ~63) | ((colA & 63) ^ ((row & 7) << 3));
        af[mi] = *(const s16x8*)&As[row * 512 + sc];
      }
      #pragma unroll
      for (int ni = 0; ni < 2; ++ni) {
        int m = w * 32 + ni * 16 + (lane & 15);
        bf[ni] = *(const s16x8*)&Bs[m * 32 + ((kg ^ keyf(m)) * 8)];
      }
      #pragma unroll
      for (int mi = 0; mi < 2; ++mi)
        #pragma unroll
        for (int ni = 0; ni < 2; ++ni)
          acc[mi][ni] = __builtin_amdgcn_mfma_f32_16x16x32_bf16(af[mi], bf[ni], acc[mi][ni], 0, 0, 0);
      __syncthreads();
    }
  }

  if (mode == 0) {
    #pragma unroll
    for (int mi = 0; mi < 2; ++mi)
      #pragma unroll
      for (int ni = 0; ni < 2; ++ni) {
        int r0 = mi * 16 + ((lane >> 4) << 2);
        int c = w * 32 + ni * 16 + (lane & 15);
        #pragma unroll
        for (int u = 0; u < 4; ++u)
          rfq[((size_t)b * LL + l0 + r0 + u) * MM + c] = f2b(expf(acc[mi][ni][u] * 0.03125f) * 0.0625f);
      }
  } else {
    // bounce C^T into As overlay [256 m][40 l-pad], fused Z partials
    short* T = &As[0];
    float zp[2] = {0.f, 0.f};
    #pragma unroll
    for (int mi = 0; mi < 2; ++mi)
      #pragma unroll
      for (int ni = 0; ni < 2; ++ni) {
        int l = mi * 16 + ((lane >> 4) << 2);
        int m = w * 32 + ni * 16 + (lane & 15);
        float e0 = expf(acc[mi][ni][0] * 0.03125f);
        float e1 = expf(acc[mi][ni][1] * 0.03125f);
        float e2 = expf(acc[mi][ni][2] * 0.03125f);
        float e3 = expf(acc[mi][ni][3] * 0.03125f);
        zp[ni] += e0 + e1 + e2 + e3;
        unsigned p0 = ((unsigned)(unsigned short)f2b(e0)) | (((unsigned)(unsigned short)f2b(e1)) << 16);
        unsigned p1 = ((unsigned)(unsigned short)f2b(e2)) | (((unsigned)(unsigned short)f2b(e3)) << 16);
        *(unsigned*)&T[m * 40 + l] = p0;
        *(unsigned*)&T[m * 40 + l + 2] = p1;
      }
    zp[0] += __shfl_xor(zp[0], 16); zp[0] += __shfl_xor(zp[0], 32);
    zp[1] += __shfl_xor(zp[1], 16); zp[1] += __shfl_xor(zp[1], 32);
    if ((lane >> 4) == 0) {
      atomicAdd(&Zz[b * MM + w * 32 + (lane & 15)], zp[0]);
      atomicAdd(&Zz[b * MM + w * 32 + 16 + (lane & 15)], zp[1]);
    }
    __syncthreads();
    int m = tid >> 1, lh = (tid & 1) * 16;
    s16x8 v0 = *(const s16x8*)&T[m * 40 + lh];
    s16x8 v1 = *(const s16x8*)&T[m * 40 + lh + 8];
    short* dst = rfkT + ((size_t)b * MM + m) * LL + l0 + lh;
    *(s16x8*)dst = v0;
    *(s16x8*)(dst + 8) = v1;
  }
}

// ---------------- KVT[b][d][m] += sum_l V[l][d]*rfkT[m][l]; V read as 512B row slices ----------------
__global__ __launch_bounds__(512, 2) void k_kv(const float* __restrict__ V, const short* __restrict__ rfkT,
                                               float* __restrict__ KVTf) {
  __shared__ short Ak[2][256 * 32];   // rfkT tile [256 m][32 l], 4-chunk swizzled, 16 KB x2
  __shared__ short Vt[2][128 * 40];   // V^T tile [128 d][32 l] pad-40, 10 KB x2
  int d0 = blockIdx.x * 128, ls = blockIdx.y * 256, b = blockIdx.z;
  int tid = threadIdx.x, lane = tid & 63, w = tid >> 6;
  int wm = w >> 1, wd = w & 1;   // 4(m) x 2(d)

  int vl = tid >> 4, vd = (tid & 15) * 8;
  const float* Vb = V + ((size_t)b * LL + ls + vl) * DD + d0 + vd;

  int am = tid >> 2, as = tid & 3;
  int acs = as ^ keyf(am);
  const short* AkS0 = rfkT + ((size_t)b * MM + am) * LL + ls + acs * 8;
  const short* AkS1 = rfkT + ((size_t)b * MM + am + 128) * LL + ls + acs * 8;

  fx4 acc[4][4] = {};
  float4 pv0, pv1;

  // prologue: chunk 0
  pv0 = *(const float4*)(Vb);
  pv1 = *(const float4*)(Vb + 4);
  GLL16(AkS0, &Ak[0][tid * 8]);
  GLL16(AkS1, &Ak[0][(tid + 512) * 8]);
  #pragma unroll
  for (int j = 0; j < 4; ++j) {
    Vt[0][(vd + j) * 40 + vl] = f2b(((const float*)&pv0)[j]);
    Vt[0][(vd + 4 + j) * 40 + vl] = f2b(((const float*)&pv1)[j]);
  }
  __syncthreads();

  for (int ch = 0; ch < 8; ++ch) {
    int cur = ch & 1, nxt = cur ^ 1;
    if (ch < 7) {
      int lo = (ch + 1) * 32;
      pv0 = *(const float4*)(Vb + (size_t)lo * DD);
      pv1 = *(const float4*)(Vb + (size_t)lo * DD + 4);
      GLL16(AkS0 + lo, &Ak[nxt][tid * 8]);
      GLL16(AkS1 + lo, &Ak[nxt][(tid + 512) * 8]);
    }
    int kg = lane >> 4;
    s16x8 af[4], bf[4];
    #pragma unroll
    for (int mi = 0; mi < 4; ++mi) {
      int m = wm * 64 + mi * 16 + (lane & 15);
      af[mi] = *(const s16x8*)&Ak[cur][m * 32 + ((kg ^ keyf(m)) * 8)];
    }
    #pragma unroll
    for (int ni = 0; ni < 4; ++ni) {
      int d = wd * 64 + ni * 16 + (lane & 15);
      bf[ni] = *(const s16x8*)&Vt[cur][d * 40 + kg * 8];
    }
    #pragma unroll
    for (int mi = 0; mi < 4; ++mi)
      #pragma unroll
      for (int ni = 0; ni < 4; ++ni)
        acc[mi][ni] = __builtin_amdgcn_mfma_f32_16x16x32_bf16(af[mi], bf[ni], acc[mi][ni], 0, 0, 0);
    if (ch < 7) {
      #pragma unroll
      for (int j = 0; j < 4; ++j) {
        Vt[nxt][(vd + j) * 40 + vl] = f2b(((const float*)&pv0)[j]);
        Vt[nxt][(vd + 4 + j) * 40 + vl] = f2b(((const float*)&pv1)[j]);
      }
      __syncthreads();
    }
  }
  #pragma unroll
  for (int mi = 0; mi < 4; ++mi)
    #pragma unroll
    for (int ni = 0; ni < 4; ++ni) {
      int d = d0 + wd * 64 + ni * 16 + (lane & 15);
      int m = wm * 64 + mi * 16 + ((lane >> 4) << 2);
      #pragma unroll
      for (int u = 0; u < 4; ++u)
        atomicAdd(&KVTf[((size_t)b * DD + d) * MM + m + u], acc[mi][ni][u]);
    }
}

// ---------------- out = (rf_q x KVT^T) / (rf_q . Z + eps); KVTf read fp32 ----------------
__global__ __launch_bounds__(512) void k_out(const short* __restrict__ rfq, const float* __restrict__ KVTf,
                                             const float* __restrict__ Zz, float* __restrict__ out) {
  __shared__ short Aq[2][8192];   // [128 l][64 m]
  __shared__ short Bv[2][8192];   // [128 d][64 m]
  __shared__ float zl[256];
  __shared__ float np[512];
  __shared__ float nf[128];
  int l0 = blockIdx.x * 128, d0 = blockIdx.y * 128, b = blockIdx.z;
  int tid = threadIdx.x, lane = tid & 63, w = tid >> 6;
  int wr = w >> 2, wc = w & 3;               // 2(l) x 4(d)
  int brow = tid >> 2, bq = (tid & 3) * 16;
  int bkey = (brow & 7) << 3;
  const float* Kf = KVTf + ((size_t)b * DD + d0 + brow) * MM + bq;
  short* Bw0 = &Bv[0][brow * 64 + (bq ^ bkey)];
  short* Bw1 = &Bv[0][brow * 64 + ((bq + 8) ^ bkey)];
  const short* Ab = rfq + ((size_t)b * LL + l0) * MM;
  int f1 = tid + 512;
  int ar0 = tid >> 3, ac0 = tid & 7, ar1 = f1 >> 3, ac1 = f1 & 7;
  int nrow = tid & 127, nsub = tid >> 7;
  if (tid < 256) zl[tid] = Zz[b * MM + tid];
  fx4 acc[4][2] = {};
  float4 pb[4];
  float na = 0.f;

  #pragma unroll
  for (int i = 0; i < 4; ++i) pb[i] = *(const float4*)(Kf + i * 4);
  GLL16(Ab + (size_t)ar0 * MM + (ac0 ^ (ar0 & 7)) * 8, &Aq[0][tid * 8]);
  GLL16(Ab + (size_t)ar1 * MM + (ac1 ^ (ar1 & 7)) * 8, &Aq[0][f1 * 8]);
  {
    u32x2 v0, v1;
    v0[0] = cvt2(pb[0].x, pb[0].y); v0[1] = cvt2(pb[0].z, pb[0].w);
    v1[0] = cvt2(pb[1].x, pb[1].y); v1[1] = cvt2(pb[1].z, pb[1].w);
    *(u32x2*)Bw0 = v0;
    *(u32x2*)(Bw0 + 4) = v1;
    v0[0] = cvt2(pb[2].x, pb[2].y); v0[1] = cvt2(pb[2].z, pb[2].w);
    v1[0] = cvt2(pb[3].x, pb[3].y); v1[1] = cvt2(pb[3].z, pb[3].w);
    *(u32x2*)Bw1 = v0;
    *(u32x2*)(Bw1 + 4) = v1;
  }
  __syncthreads();

  for (int t = 0; t < 4; ++t) {
    int cur = t & 1, nxt = cur ^ 1;
    int m1 = ((t + 1) & 3) * 64;
    #pragma unroll
    for (int i = 0; i < 4; ++i) pb[i] = *(const float4*)(Kf + m1 + i * 4);
    GLL16(Ab + (size_t)ar0 * MM + m1 + (ac0 ^ (ar0 & 7)) * 8, &Aq[nxt][tid * 8]);
    GLL16(Ab + (size_t)ar1 * MM + m1 + (ac1 ^ (ar1 & 7)) * 8, &Aq[nxt][f1 * 8]);
    #pragma unroll
    for (int kk = 0; kk < 16; ++kk) {
      int k = nsub * 16 + kk;
      na += b2f(Aq[cur][nrow * 64 + (k ^ ((nrow & 7) << 3))]) * zl[t * 64 + k];
    }
    #pragma unroll
    for (int ks = 0; ks < 2; ++ks) {
      int kb = ks * 32 + (lane >> 4) * 8;
      s16x8 af[4], bf[2];
      #pragma unroll
      for (int mi = 0; mi < 4; ++mi) {
        int row = wr * 64 + mi * 16 + (lane & 15);
        af[mi] = *(const s16x8*)&Aq[cur][row * 64 + (kb ^ ((row & 7) << 3))];
      }
      #pragma unroll
      for (int ni = 0; ni < 2; ++ni) {
        int row = wc * 32 + ni * 16 + (lane & 15);
        bf[ni] = *(const s16x8*)&Bv[cur][row * 64 + (kb ^ ((row & 7) << 3))];
      }
      #pragma unroll
      for (int mi = 0; mi < 4; ++mi)
        #pragma unroll
        for (int ni = 0; ni < 2; ++ni)
          acc[mi][ni] = __builtin_amdgcn_mfma_f32_16x16x32_bf16(af[mi], bf[ni], acc[mi][ni], 0, 0, 0);
    }
    {
      u32x2 v0, v1;
      v0[0] = cvt2(pb[0].x, pb[0].y); v0[1] = cvt2(pb[0].z, pb[0].w);
      v1[0] = cvt2(pb[1].x, pb[1].y); v1[1] = cvt2(pb[1].z, pb[1].w);
      *(u32x2*)(Bw0 + nxt * 8192) = v0;
      *(u32x2*)(Bw0 + nxt * 8192 + 4) = v1;
      v0[0] = cvt2(pb[2].x, pb[2].y); v0[1] = cvt2(pb[2].z, pb[2].w);
      v1[0] = cvt2(pb[3].x, pb[3].y); v1[1] = cvt2(pb[3].z, pb[3].w);
      *(u32x2*)(Bw1 + nxt * 8192) = v0;
      *(u32x2*)(Bw1 + nxt * 8192 + 4) = v1;
    }
    __syncthreads();
  }
  np[tid] = na;
  __syncthreads();
  if (tid < 128) nf[tid] = np[tid] + np[tid + 128] + np[tid + 256] + np[tid + 384] + 1e-6f;
  __syncthreads();
  #pragma unroll
  for (int mi = 0; mi < 4; ++mi)
    #pragma unroll
    for (int ni = 0; ni < 2; ++ni) {
      int l = wr * 64 + mi * 16 + ((lane >> 4) << 2);
      int d = d0 + wc * 32 + ni * 16 + (lane & 15);
      #pragma unroll
      for (int u = 0; u < 4; ++u)
        out[((size_t)b * LL + l0 + l + u) * DD + d] = acc[mi][ni][u] / nf[l + u];
    }
}

extern "C" void kernel_launch(void* const* d_in, const int* in_sizes, int n_in,
                              void* d_out, int out_size, void* d_ws, size_t ws_size,
                              hipStream_t stream) {
  const float* Q = (const float*)d_in[0];
  const float* K = (const float*)d_in[1];
  const float* V = (const float*)d_in[2];
  const float* P = (const float*)d_in[3];
  float* out = (float*)d_out;
  char* ws = (char*)d_ws;

  short* Pb   = (short*)(ws + 0);          // 256*1024*2    = 512 KB
  float* Zz   = (float*)(ws + 524288);     // 4*256*4       = 4 KB
  float* KVTf = (float*)(ws + 528384);     // 4*1024*256*4  = 4 MB
  short* rfq  = (short*)(ws + 4722688);    // 4*4096*256*2  = 8 MB
  short* rfkT = (short*)(ws + 13111296);   // 4*256*4096*2  = 8 MB

  k_cast<<<256, 256, 0, stream>>>(P, Pb, 65536);
  (void)hipMemsetAsync(ws + 524288, 0, 4096 + (size_t)NB * DD * MM * sizeof(float), stream);
  k_qk<<<dim3(128, 1, 2 * NB), 512, 0, stream>>>(Q, K, Pb, rfq, rfkT, Zz);
  k_kv<<<dim3(8, 16, NB), 512, 0, stream>>>(V, rfkT, KVTf);
  k_out<<<dim3(32, 8, NB), 512, 0, stream>>>(rfq, KVTf, Zz, out);
}

// Round 5
// 172.135 us; speedup vs baseline: 2.0206x; 2.0206x over previous
//
#include <hip/hip_runtime.h>
#include <math.h>

#define NB 4
#define LL 4096
#define DD 1024
#define MM 256

typedef short s16x8 __attribute__((ext_vector_type(8)));
typedef short s16x4 __attribute__((ext_vector_type(4)));
typedef float fx4 __attribute__((ext_vector_type(4)));
typedef unsigned u32x2 __attribute__((ext_vector_type(2)));
typedef unsigned u32x4 __attribute__((ext_vector_type(4)));

__device__ __forceinline__ float b2f(short s) {
  union { unsigned u; float f; } v;
  v.u = ((unsigned)(unsigned short)s) << 16;
  return v.f;
}
__device__ __forceinline__ short f2b(float f) {
  union { float f; unsigned u; } v;
  v.f = f;
  unsigned r = (v.u + 0x7fffu + ((v.u >> 16) & 1u)) >> 16;
  return (short)(unsigned short)r;
}
// packed fp32->bf16 (RNE), 2 values per instruction
__device__ __forceinline__ unsigned cvt2(float lo, float hi) {
  unsigned r;
  asm("v_cvt_pk_bf16_f32 %0, %1, %2" : "=v"(r) : "v"(lo), "v"(hi));
  return r;
}
// 4-chunk swizzle key for 32-k-wide GLL16 tiles
__device__ __forceinline__ int keyf(int m) { return (m ^ (m >> 2)) & 3; }

typedef __attribute__((address_space(1))) const void* gas1_t;
typedef __attribute__((address_space(3))) void* las3_t;
#define GLL16(g, l) __builtin_amdgcn_global_load_lds((gas1_t)(const void*)(g), (las3_t)(void*)(l), 16, 0, 0)

// ---------------- cast fp32 -> bf16 (P only) ----------------
__global__ __launch_bounds__(256) void k_cast(const float* __restrict__ in, short* __restrict__ out, int n4) {
  int i = blockIdx.x * 256 + threadIdx.x;
  if (i >= n4) return;
  float4 v = ((const float4*)in)[i];
  s16x4 s;
  s[0] = f2b(v.x); s[1] = f2b(v.y); s[2] = f2b(v.z); s[3] = f2b(v.w);
  ((s16x4*)out)[i] = s;
}

// ---------------- rf GEMM: [32 l] x [256 m]; A LDS-resident per K-half, B direct from L2 ----------------
// z<4: rf_q (B,L,M) incl 1/sqrt(M); z>=4: rf_kT (B,M,L) + Z atomics (tiny).
__global__ __launch_bounds__(512, 4) void k_qk(const float* __restrict__ Q, const float* __restrict__ K,
                                               const short* __restrict__ Pb,
                                               short* __restrict__ rfq, short* __restrict__ rfkT,
                                               float* __restrict__ Zz) {
  __shared__ short As[32 * 512];   // 32 KB: [32 l][512 k], 8-granule XOR swizzle by row&7
  int z = blockIdx.z, mode = z >> 2, b = z & 3;
  int l0 = blockIdx.x * 32;
  const float* X = mode ? K : Q;
  int tid = threadIdx.x, lane = tid & 63, w = tid >> 6;
  int m16 = lane & 15, kg = lane >> 4;

  fx4 acc[2][2] = {};

  for (int h = 0; h < 2; ++h) {
    if (h) __syncthreads();
    // stage A half: 32 rows x 512 k, contiguous 2KB per row
    const float* Xb = X + ((size_t)b * LL + l0) * DD + h * 512;
    float4 pa[8];
    #pragma unroll
    for (int i = 0; i < 8; ++i) {
      int g = i * 512 + tid;
      pa[i] = *(const float4*)(Xb + (size_t)(g >> 7) * DD + (g & 127) * 4);
    }
    #pragma unroll
    for (int i = 0; i < 8; ++i) {
      int g = i * 512 + tid, row = g >> 7, col = (g & 127) * 4;
      int sc = (col & ~63) | ((col & 63) ^ ((row & 7) << 3));
      u32x2 vv;
      vv[0] = cvt2(pa[i].x, pa[i].y);
      vv[1] = cvt2(pa[i].z, pa[i].w);
      *(u32x2*)&As[row * 512 + sc] = vv;
    }
    __syncthreads();

    // B fragment pointers: direct global (Pb is L2-resident)
    const short* pB0 = Pb + (size_t)(w * 32 + m16) * DD + h * 512 + kg * 8;
    const short* pB1 = pB0 + 16 * DD;
    s16x8 bA0 = *(const s16x8*)pB0;
    s16x8 bA1 = *(const s16x8*)pB1;
    s16x8 bB0 = *(const s16x8*)(pB0 + 32);
    s16x8 bB1 = *(const s16x8*)(pB1 + 32);

    #pragma unroll
    for (int st = 0; st < 16; st += 2) {
      // even step
      {
        s16x8 c0 = bA0, c1 = bA1;
        if (st < 14) { bA0 = *(const s16x8*)(pB0 + (st + 2) * 32); bA1 = *(const s16x8*)(pB1 + (st + 2) * 32); }
        int colA = st * 32 + kg * 8;
        int sc = (colA & ~63) | ((colA & 63) ^ ((m16 & 7) << 3));
        s16x8 af0 = *(const s16x8*)&As[m16 * 512 + sc];
        s16x8 af1 = *(const s16x8*)&As[(16 + m16) * 512 + sc];
        acc[0][0] = __builtin_amdgcn_mfma_f32_16x16x32_bf16(af0, c0, acc[0][0], 0, 0, 0);
        acc[0][1] = __builtin_amdgcn_mfma_f32_16x16x32_bf16(af0, c1, acc[0][1], 0, 0, 0);
        acc[1][0] = __builtin_amdgcn_mfma_f32_16x16x32_bf16(af1, c0, acc[1][0], 0, 0, 0);
        acc[1][1] = __builtin_amdgcn_mfma_f32_16x16x32_bf16(af1, c1, acc[1][1], 0, 0, 0);
      }
      // odd step
      {
        s16x8 c0 = bB0, c1 = bB1;
        if (st < 14) { bB0 = *(const s16x8*)(pB0 + (st + 3) * 32); bB1 = *(const s16x8*)(pB1 + (st + 3) * 32); }
        int colA = (st + 1) * 32 + kg * 8;
        int sc = (colA & ~63) | ((colA & 63) ^ ((m16 & 7) << 3));
        s16x8 af0 = *(const s16x8*)&As[m16 * 512 + sc];
        s16x8 af1 = *(const s16x8*)&As[(16 + m16) * 512 + sc];
        acc[0][0] = __builtin_amdgcn_mfma_f32_16x16x32_bf16(af0, c0, acc[0][0], 0, 0, 0);
        acc[0][1] = __builtin_amdgcn_mfma_f32_16x16x32_bf16(af0, c1, acc[0][1], 0, 0, 0);
        acc[1][0] = __builtin_amdgcn_mfma_f32_16x16x32_bf16(af1, c0, acc[1][0], 0, 0, 0);
        acc[1][1] = __builtin_amdgcn_mfma_f32_16x16x32_bf16(af1, c1, acc[1][1], 0, 0, 0);
      }
    }
  }

  if (mode == 0) {
    #pragma unroll
    for (int mi = 0; mi < 2; ++mi)
      #pragma unroll
      for (int ni = 0; ni < 2; ++ni) {
        int r0 = mi * 16 + (kg << 2);
        int c = w * 32 + ni * 16 + m16;
        #pragma unroll
        for (int u = 0; u < 4; ++u)
          rfq[((size_t)b * LL + l0 + r0 + u) * MM + c] = f2b(expf(acc[mi][ni][u] * 0.03125f) * 0.0625f);
      }
  } else {
    // bounce C^T into As overlay [256 m][40 l-pad], fused Z partials
    short* T = &As[0];
    float zp[2] = {0.f, 0.f};
    __syncthreads();
    #pragma unroll
    for (int mi = 0; mi < 2; ++mi)
      #pragma unroll
      for (int ni = 0; ni < 2; ++ni) {
        int l = mi * 16 + (kg << 2);
        int m = w * 32 + ni * 16 + m16;
        float e0 = expf(acc[mi][ni][0] * 0.03125f);
        float e1 = expf(acc[mi][ni][1] * 0.03125f);
        float e2 = expf(acc[mi][ni][2] * 0.03125f);
        float e3 = expf(acc[mi][ni][3] * 0.03125f);
        zp[ni] += e0 + e1 + e2 + e3;
        *(unsigned*)&T[m * 40 + l] = cvt2(e0, e1);
        *(unsigned*)&T[m * 40 + l + 2] = cvt2(e2, e3);
      }
    zp[0] += __shfl_xor(zp[0], 16); zp[0] += __shfl_xor(zp[0], 32);
    zp[1] += __shfl_xor(zp[1], 16); zp[1] += __shfl_xor(zp[1], 32);
    if (kg == 0) {
      atomicAdd(&Zz[b * MM + w * 32 + m16], zp[0]);
      atomicAdd(&Zz[b * MM + w * 32 + 16 + m16], zp[1]);
    }
    __syncthreads();
    int m = tid >> 1, lh = (tid & 1) * 16;
    s16x8 v0 = *(const s16x8*)&T[m * 40 + lh];
    s16x8 v1 = *(const s16x8*)&T[m * 40 + lh + 8];
    short* dst = rfkT + ((size_t)b * MM + m) * LL + l0 + lh;
    *(s16x8*)dst = v0;
    *(s16x8*)(dst + 8) = v1;
  }
}

// ---------------- KV partials: KVp[kc][b][d][m] = sum over 512 l; NO atomics ----------------
__global__ __launch_bounds__(512) void k_kv(const float* __restrict__ V, const short* __restrict__ rfkT,
                                            float* __restrict__ KVp) {
  __shared__ float Vs[2][32 * 129];   // fp32 [32 l][129 d-pitch] (odd pitch: conflict-free col reads)
  __shared__ short Ak[2][256 * 32];   // rfkT [256 m][32 l] bf16, 4-chunk swizzled
  int d0 = blockIdx.x * 128, kc = blockIdx.y, b = blockIdx.z;
  int ls = kc * 512;
  int tid = threadIdx.x, lane = tid & 63, w = tid >> 6;
  int wm = w >> 1, wd = w & 1;     // 4(m) x 2(d)
  int m16 = lane & 15, kg = lane >> 4;

  int vl = tid >> 4, vf = (tid & 15) * 8;
  const float* Vb = V + ((size_t)b * LL + ls + vl) * DD + d0 + vf;

  int am = tid >> 2, as = tid & 3;
  int acs = as ^ keyf(am);
  const short* AkS0 = rfkT + ((size_t)b * MM + am) * LL + ls + acs * 8;
  const short* AkS1 = rfkT + ((size_t)b * MM + am + 128) * LL + ls + acs * 8;

  fx4 acc[4][4] = {};
  float4 pv0, pv1;

  // prologue: chunk 0
  pv0 = *(const float4*)(Vb);
  pv1 = *(const float4*)(Vb + 4);
  GLL16(AkS0, &Ak[0][tid * 8]);
  GLL16(AkS1, &Ak[0][(tid + 512) * 8]);
  #pragma unroll
  for (int j = 0; j < 4; ++j) {
    Vs[0][vl * 129 + vf + j] = ((const float*)&pv0)[j];
    Vs[0][vl * 129 + vf + 4 + j] = ((const float*)&pv1)[j];
  }
  __syncthreads();

  for (int ch = 0; ch < 16; ++ch) {
    int cur = ch & 1, nxt = cur ^ 1;
    if (ch < 15) {
      int lo = (ch + 1) * 32;
      pv0 = *(const float4*)(Vb + (size_t)lo * DD);
      pv1 = *(const float4*)(Vb + (size_t)lo * DD + 4);
      GLL16(AkS0 + lo, &Ak[nxt][tid * 8]);
      GLL16(AkS1 + lo, &Ak[nxt][(tid + 512) * 8]);
    }
    s16x8 af[4];
    #pragma unroll
    for (int mi = 0; mi < 4; ++mi) {
      int m = wm * 64 + mi * 16 + m16;
      af[mi] = *(const s16x8*)&Ak[cur][m * 32 + ((kg ^ keyf(m)) * 8)];
    }
    #pragma unroll
    for (int ni = 0; ni < 4; ++ni) {
      int d = wd * 64 + ni * 16 + m16;
      const float* vs = &Vs[cur][kg * 8 * 129 + d];
      u32x4 bw;
      bw[0] = cvt2(vs[0], vs[129]);
      bw[1] = cvt2(vs[258], vs[387]);
      bw[2] = cvt2(vs[516], vs[645]);
      bw[3] = cvt2(vs[774], vs[903]);
      s16x8 bf = *(s16x8*)&bw;
      #pragma unroll
      for (int mi = 0; mi < 4; ++mi)
        acc[mi][ni] = __builtin_amdgcn_mfma_f32_16x16x32_bf16(af[mi], bf, acc[mi][ni], 0, 0, 0);
    }
    if (ch < 15) {
      #pragma unroll
      for (int j = 0; j < 4; ++j) {
        Vs[nxt][vl * 129 + vf + j] = ((const float*)&pv0)[j];
        Vs[nxt][vl * 129 + vf + 4 + j] = ((const float*)&pv1)[j];
      }
    }
    __syncthreads();
  }

  // non-atomic partial store: [kc][b][d][m], float4 along m
  float* dst = KVp + (((size_t)kc * NB + b) * DD + d0) * MM;
  #pragma unroll
  for (int mi = 0; mi < 4; ++mi)
    #pragma unroll
    for (int ni = 0; ni < 4; ++ni) {
      int d = wd * 64 + ni * 16 + m16;
      int m = wm * 64 + mi * 16 + (kg << 2);
      *(float4*)(dst + (size_t)d * MM + m) = *(float4*)&acc[mi][ni];
    }
}

// ---------------- reduce 8 split-K partials -> KVTf fp32 ----------------
__global__ __launch_bounds__(256) void k_red(const float* __restrict__ KVp, float* __restrict__ KVTf) {
  int i = blockIdx.x * 256 + threadIdx.x;
  const float4* p = (const float4*)KVp;
  float4 s = p[i];
  #pragma unroll
  for (int k = 1; k < 8; ++k) {
    float4 v = p[i + k * 262144];
    s.x += v.x; s.y += v.y; s.z += v.z; s.w += v.w;
  }
  ((float4*)KVTf)[i] = s;
}

// ---------------- out = (rf_q x KVT^T) / (rf_q . Z + eps); KVTf read fp32 ----------------
__global__ __launch_bounds__(512) void k_out(const short* __restrict__ rfq, const float* __restrict__ KVTf,
                                             const float* __restrict__ Zz, float* __restrict__ out) {
  __shared__ short Aq[2][8192];   // [128 l][64 m]
  __shared__ short Bv[2][8192];   // [128 d][64 m]
  __shared__ float zl[256];
  __shared__ float np[512];
  __shared__ float nf[128];
  int l0 = blockIdx.x * 128, d0 = blockIdx.y * 128, b = blockIdx.z;
  int tid = threadIdx.x, lane = tid & 63, w = tid >> 6;
  int wr = w >> 2, wc = w & 3;               // 2(l) x 4(d)
  int brow = tid >> 2, bq = (tid & 3) * 16;
  int bkey = (brow & 7) << 3;
  const float* Kf = KVTf + ((size_t)b * DD + d0 + brow) * MM + bq;
  short* Bw0 = &Bv[0][brow * 64 + (bq ^ bkey)];
  short* Bw1 = &Bv[0][brow * 64 + ((bq + 8) ^ bkey)];
  const short* Ab = rfq + ((size_t)b * LL + l0) * MM;
  int f1 = tid + 512;
  int ar0 = tid >> 3, ac0 = tid & 7, ar1 = f1 >> 3, ac1 = f1 & 7;
  int nrow = tid & 127, nsub = tid >> 7;
  if (tid < 256) zl[tid] = Zz[b * MM + tid];
  fx4 acc[4][2] = {};
  float4 pb[4];
  float na = 0.f;

  #pragma unroll
  for (int i = 0; i < 4; ++i) pb[i] = *(const float4*)(Kf + i * 4);
  GLL16(Ab + (size_t)ar0 * MM + (ac0 ^ (ar0 & 7)) * 8, &Aq[0][tid * 8]);
  GLL16(Ab + (size_t)ar1 * MM + (ac1 ^ (ar1 & 7)) * 8, &Aq[0][f1 * 8]);
  {
    u32x2 v0, v1;
    v0[0] = cvt2(pb[0].x, pb[0].y); v0[1] = cvt2(pb[0].z, pb[0].w);
    v1[0] = cvt2(pb[1].x, pb[1].y); v1[1] = cvt2(pb[1].z, pb[1].w);
    *(u32x2*)Bw0 = v0;
    *(u32x2*)(Bw0 + 4) = v1;
    v0[0] = cvt2(pb[2].x, pb[2].y); v0[1] = cvt2(pb[2].z, pb[2].w);
    v1[0] = cvt2(pb[3].x, pb[3].y); v1[1] = cvt2(pb[3].z, pb[3].w);
    *(u32x2*)Bw1 = v0;
    *(u32x2*)(Bw1 + 4) = v1;
  }
  __syncthreads();

  for (int t = 0; t < 4; ++t) {
    int cur = t & 1, nxt = cur ^ 1;
    int m1 = ((t + 1) & 3) * 64;
    #pragma unroll
    for (int i = 0; i < 4; ++i) pb[i] = *(const float4*)(Kf + m1 + i * 4);
    GLL16(Ab + (size_t)ar0 * MM + m1 + (ac0 ^ (ar0 & 7)) * 8, &Aq[nxt][tid * 8]);
    GLL16(Ab + (size_t)ar1 * MM + m1 + (ac1 ^ (ar1 & 7)) * 8, &Aq[nxt][f1 * 8]);
    #pragma unroll
    for (int kk = 0; kk < 16; ++kk) {
      int k = nsub * 16 + kk;
      na += b2f(Aq[cur][nrow * 64 + (k ^ ((nrow & 7) << 3))]) * zl[t * 64 + k];
    }
    #pragma unroll
    for (int ks = 0; ks < 2; ++ks) {
      int kb = ks * 32 + (lane >> 4) * 8;
      s16x8 af[4], bf[2];
      #pragma unroll
      for (int mi = 0; mi < 4; ++mi) {
        int row = wr * 64 + mi * 16 + (lane & 15);
        af[mi] = *(const s16x8*)&Aq[cur][row * 64 + (kb ^ ((row & 7) << 3))];
      }
      #pragma unroll
      for (int ni = 0; ni < 2; ++ni) {
        int row = wc * 32 + ni * 16 + (lane & 15);
        bf[ni] = *(const s16x8*)&Bv[cur][row * 64 + (kb ^ ((row & 7) << 3))];
      }
      #pragma unroll
      for (int mi = 0; mi < 4; ++mi)
        #pragma unroll
        for (int ni = 0; ni < 2; ++ni)
          acc[mi][ni] = __builtin_amdgcn_mfma_f32_16x16x32_bf16(af[mi], bf[ni], acc[mi][ni], 0, 0, 0);
    }
    {
      u32x2 v0, v1;
      v0[0] = cvt2(pb[0].x, pb[0].y); v0[1] = cvt2(pb[0].z, pb[0].w);
      v1[0] = cvt2(pb[1].x, pb[1].y); v1[1] = cvt2(pb[1].z, pb[1].w);
      *(u32x2*)(Bw0 + nxt * 8192) = v0;
      *(u32x2*)(Bw0 + nxt * 8192 + 4) = v1;
      v0[0] = cvt2(pb[2].x, pb[2].y); v0[1] = cvt2(pb[2].z, pb[2].w);
      v1[0] = cvt2(pb[3].x, pb[3].y); v1[1] = cvt2(pb[3].z, pb[3].w);
      *(u32x2*)(Bw1 + nxt * 8192) = v0;
      *(u32x2*)(Bw1 + nxt * 8192 + 4) = v1;
    }
    __syncthreads();
  }
  np[tid] = na;
  __syncthreads();
  if (tid < 128) nf[tid] = np[tid] + np[tid + 128] + np[tid + 256] + np[tid + 384] + 1e-6f;
  __syncthreads();
  #pragma unroll
  for (int mi = 0; mi < 4; ++mi)
    #pragma unroll
    for (int ni = 0; ni < 2; ++ni) {
      int l = wr * 64 + mi * 16 + ((lane >> 4) << 2);
      int d = d0 + wc * 32 + ni * 16 + (lane & 15);
      #pragma unroll
      for (int u = 0; u < 4; ++u)
        out[((size_t)b * LL + l0 + l + u) * DD + d] = acc[mi][ni][u] / nf[l + u];
    }
}

extern "C" void kernel_launch(void* const* d_in, const int* in_sizes, int n_in,
                              void* d_out, int out_size, void* d_ws, size_t ws_size,
                              hipStream_t stream) {
  const float* Q = (const float*)d_in[0];
  const float* K = (const float*)d_in[1];
  const float* V = (const float*)d_in[2];
  const float* P = (const float*)d_in[3];
  float* out = (float*)d_out;
  char* ws = (char*)d_ws;

  short* Pb   = (short*)(ws + 0);          // 256*1024*2    = 512 KB
  float* Zz   = (float*)(ws + 524288);     // 4*256*4       = 4 KB
  float* KVTf = (float*)(ws + 528384);     // 4*1024*256*4  = 4 MB
  short* rfq  = (short*)(ws + 4722688);    // 4*4096*256*2  = 8 MB
  short* rfkT = (short*)(ws + 13111296);   // 4*256*4096*2  = 8 MB
  float* KVp  = (float*)(ws + 21499904);   // 8*4*1024*256*4 = 32 MB

  k_cast<<<256, 256, 0, stream>>>(P, Pb, 65536);
  (void)hipMemsetAsync(Zz, 0, 4096, stream);
  k_qk<<<dim3(128, 1, 2 * NB), 512, 0, stream>>>(Q, K, Pb, rfq, rfkT, Zz);
  k_kv<<<dim3(8, 8, NB), 512, 0, stream>>>(V, rfkT, KVp);
  k_red<<<1024, 256, 0, stream>>>(KVp, KVTf);
  k_out<<<dim3(32, 8, NB), 512, 0, stream>>>(rfq, KVTf, Zz, out);
}

// Round 6
// 152.656 us; speedup vs baseline: 2.2785x; 1.1276x over previous
//
#include <hip/hip_runtime.h>
#include <math.h>

#define NB 4
#define LL 4096
#define DD 1024
#define MM 256

typedef short s16x8 __attribute__((ext_vector_type(8)));
typedef short s16x4 __attribute__((ext_vector_type(4)));
typedef float fx4 __attribute__((ext_vector_type(4)));
typedef unsigned u32x2 __attribute__((ext_vector_type(2)));
typedef unsigned u32x4 __attribute__((ext_vector_type(4)));

__device__ __forceinline__ float b2f(short s) {
  union { unsigned u; float f; } v;
  v.u = ((unsigned)(unsigned short)s) << 16;
  return v.f;
}
__device__ __forceinline__ short f2b(float f) {
  union { float f; unsigned u; } v;
  v.f = f;
  unsigned r = (v.u + 0x7fffu + ((v.u >> 16) & 1u)) >> 16;
  return (short)(unsigned short)r;
}
// packed fp32->bf16 (RNE), 2 values per instruction
__device__ __forceinline__ unsigned cvt2(float lo, float hi) {
  unsigned r;
  asm("v_cvt_pk_bf16_f32 %0, %1, %2" : "=v"(r) : "v"(lo), "v"(hi));
  return r;
}
// 64-elem (128B) rows, XOR swizzle on 8-elem granule
__device__ __forceinline__ int swz(int row, int col) {
  return row * 64 + (col ^ ((row & 7) << 3));
}
// 4-chunk swizzle key for 32-k-wide GLL16 tiles
__device__ __forceinline__ int keyf(int m) { return (m ^ (m >> 2)) & 3; }

typedef __attribute__((address_space(1))) const void* gas1_t;
typedef __attribute__((address_space(3))) void* las3_t;
#define GLL16(g, l) __builtin_amdgcn_global_load_lds((gas1_t)(const void*)(g), (las3_t)(void*)(l), 16, 0, 0)

// ---------------- cast fp32 -> bf16 (P only) ----------------
__global__ __launch_bounds__(256) void k_cast(const float* __restrict__ in, short* __restrict__ out, int n4) {
  int i = blockIdx.x * 256 + threadIdx.x;
  if (i >= n4) return;
  float4 v = ((const float4*)in)[i];
  s16x4 s;
  s[0] = f2b(v.x); s[1] = f2b(v.y); s[2] = f2b(v.z); s[3] = f2b(v.w);
  ((s16x4*)out)[i] = s;
}

// ---------------- rf GEMM, m97-replica: 128l x 128m, BK=64, 256 thr, 4 waves (2x2), dbuf ----------------
// z<4: rf_q (B,L,M) incl 1/sqrt(M); z>=4: rf_kT (B,M,L) + Z atomics.
__global__ __launch_bounds__(256, 2) void k_qk(const float* __restrict__ Q, const float* __restrict__ K,
                                               const short* __restrict__ Pb,
                                               short* __restrict__ rfq, short* __restrict__ rfkT,
                                               float* __restrict__ Zz) {
  __shared__ short As[2][8192];   // [128 l][64 k] bf16 swz, x2
  __shared__ short Bs[2][8192];   // [128 m][64 k] bf16 swz, x2
  int z = blockIdx.z, mode = z >> 2, b = z & 3;
  int m0 = blockIdx.x * 128, l0 = blockIdx.y * 128;
  const float* X = mode ? K : Q;
  int tid = threadIdx.x, lane = tid & 63, w = tid >> 6;
  int wr = w >> 1, wc = w & 1;          // 2(l) x 2(m)
  int m16 = lane & 15, kg = lane >> 4;

  // A staging: thread covers row=tid>>1, 32 contiguous k (128 B)
  int arow = tid >> 1, acolh = (tid & 1) * 32;
  int akey = (arow & 7) << 3;
  const float* Xr = X + ((size_t)b * LL + l0 + arow) * DD + acolh;
  // B staging: 4 GLL16 slots/thread, pre-swizzled source
  const short* PbB = Pb + (size_t)m0 * DD;

  fx4 acc[4][4] = {};
  float4 pa[8];

  // prologue: tile 0
  #pragma unroll
  for (int i = 0; i < 8; ++i) pa[i] = *(const float4*)(Xr + i * 4);
  #pragma unroll
  for (int j = 0; j < 4; ++j) {
    int fl = tid + j * 256, row = fl >> 3, c8 = fl & 7;
    GLL16(PbB + (size_t)row * DD + (c8 ^ (row & 7)) * 8, &Bs[0][fl * 8]);
  }
  #pragma unroll
  for (int i = 0; i < 4; ++i) {
    u32x4 vv;
    vv[0] = cvt2(pa[2 * i].x, pa[2 * i].y);
    vv[1] = cvt2(pa[2 * i].z, pa[2 * i].w);
    vv[2] = cvt2(pa[2 * i + 1].x, pa[2 * i + 1].y);
    vv[3] = cvt2(pa[2 * i + 1].z, pa[2 * i + 1].w);
    *(u32x4*)&As[0][arow * 64 + ((acolh + i * 8) ^ akey)] = vv;
  }
  __syncthreads();

  for (int t = 0; t < 16; ++t) {
    int cur = t & 1, nxt = cur ^ 1;
    if (t < 15) {
      int d1 = (t + 1) * 64;
      #pragma unroll
      for (int i = 0; i < 8; ++i) pa[i] = *(const float4*)(Xr + d1 + i * 4);
      #pragma unroll
      for (int j = 0; j < 4; ++j) {
        int fl = tid + j * 256, row = fl >> 3, c8 = fl & 7;
        GLL16(PbB + (size_t)row * DD + d1 + (c8 ^ (row & 7)) * 8, &Bs[nxt][fl * 8]);
      }
    }
    #pragma unroll
    for (int ks = 0; ks < 2; ++ks) {
      int kb = ks * 32 + kg * 8;
      s16x8 af[4], bf[4];
      #pragma unroll
      for (int mi = 0; mi < 4; ++mi) af[mi] = *(const s16x8*)&As[cur][swz(wr * 64 + mi * 16 + m16, kb)];
      #pragma unroll
      for (int ni = 0; ni < 4; ++ni) bf[ni] = *(const s16x8*)&Bs[cur][swz(wc * 64 + ni * 16 + m16, kb)];
      #pragma unroll
      for (int mi = 0; mi < 4; ++mi)
        #pragma unroll
        for (int ni = 0; ni < 4; ++ni)
          acc[mi][ni] = __builtin_amdgcn_mfma_f32_16x16x32_bf16(af[mi], bf[ni], acc[mi][ni], 0, 0, 0);
    }
    if (t < 15) {
      #pragma unroll
      for (int i = 0; i < 4; ++i) {
        u32x4 vv;
        vv[0] = cvt2(pa[2 * i].x, pa[2 * i].y);
        vv[1] = cvt2(pa[2 * i].z, pa[2 * i].w);
        vv[2] = cvt2(pa[2 * i + 1].x, pa[2 * i + 1].y);
        vv[3] = cvt2(pa[2 * i + 1].z, pa[2 * i + 1].w);
        *(u32x4*)&As[nxt][arow * 64 + ((acolh + i * 8) ^ akey)] = vv;
      }
    }
    __syncthreads();
  }

  if (mode == 0) {
    #pragma unroll
    for (int mi = 0; mi < 4; ++mi)
      #pragma unroll
      for (int ni = 0; ni < 4; ++ni) {
        int r0 = wr * 64 + mi * 16 + (kg << 2);
        int c = m0 + wc * 64 + ni * 16 + m16;
        #pragma unroll
        for (int u = 0; u < 4; ++u)
          rfq[((size_t)b * LL + l0 + r0 + u) * MM + c] = f2b(expf(acc[mi][ni][u] * 0.03125f) * 0.0625f);
      }
  } else {
    // bounce C^T into As overlay [128 m][128 l] (32 KB), fused Z partials
    short* T = (short*)As;
    float zp[4] = {0.f, 0.f, 0.f, 0.f};
    #pragma unroll
    for (int mi = 0; mi < 4; ++mi)
      #pragma unroll
      for (int ni = 0; ni < 4; ++ni) {
        int l = wr * 64 + mi * 16 + (kg << 2);
        int m = wc * 64 + ni * 16 + m16;
        int key = (m & 7) << 3;
        float e0 = expf(acc[mi][ni][0] * 0.03125f);
        float e1 = expf(acc[mi][ni][1] * 0.03125f);
        float e2 = expf(acc[mi][ni][2] * 0.03125f);
        float e3 = expf(acc[mi][ni][3] * 0.03125f);
        zp[ni] += e0 + e1 + e2 + e3;
        *(unsigned*)&T[m * 128 + (l ^ key)] = cvt2(e0, e1);
        *(unsigned*)&T[m * 128 + ((l + 2) ^ key)] = cvt2(e2, e3);
      }
    #pragma unroll
    for (int ni = 0; ni < 4; ++ni) {
      zp[ni] += __shfl_xor(zp[ni], 16);
      zp[ni] += __shfl_xor(zp[ni], 32);
    }
    if (kg == 0) {
      #pragma unroll
      for (int ni = 0; ni < 4; ++ni)
        atomicAdd(&Zz[b * MM + m0 + wc * 64 + ni * 16 + m16], zp[ni]);
    }
    __syncthreads();
    int m = tid >> 1, lh = (tid & 1) * 64;
    int mkey = (m & 7) << 3;
    short* dst = rfkT + ((size_t)b * MM + m0 + m) * LL + l0 + lh;
    #pragma unroll
    for (int j = 0; j < 8; ++j) {
      int l = lh + j * 8;
      s16x8 v = *(const s16x8*)&T[m * 128 + (l ^ mkey)];
      *(s16x8*)(dst + j * 8) = v;
    }
  }
}

// ---------------- KV partials: KVp[kc][b][d][m] = sum over 512 l; NO atomics ----------------
__global__ __launch_bounds__(512) void k_kv(const float* __restrict__ V, const short* __restrict__ rfkT,
                                            float* __restrict__ KVp) {
  __shared__ float Vs[2][32 * 129];   // fp32 [32 l][129 d-pitch] (odd pitch: conflict-free col reads)
  __shared__ short Ak[2][256 * 32];   // rfkT [256 m][32 l] bf16, 4-chunk swizzled
  int d0 = blockIdx.x * 128, kc = blockIdx.y, b = blockIdx.z;
  int ls = kc * 512;
  int tid = threadIdx.x, lane = tid & 63, w = tid >> 6;
  int wm = w >> 1, wd = w & 1;     // 4(m) x 2(d)
  int m16 = lane & 15, kg = lane >> 4;

  int vl = tid >> 4, vf = (tid & 15) * 8;
  const float* Vb = V + ((size_t)b * LL + ls + vl) * DD + d0 + vf;

  int am = tid >> 2, as = tid & 3;
  int acs = as ^ keyf(am);
  const short* AkS0 = rfkT + ((size_t)b * MM + am) * LL + ls + acs * 8;
  const short* AkS1 = rfkT + ((size_t)b * MM + am + 128) * LL + ls + acs * 8;

  fx4 acc[4][4] = {};
  float4 pv0, pv1;

  pv0 = *(const float4*)(Vb);
  pv1 = *(const float4*)(Vb + 4);
  GLL16(AkS0, &Ak[0][tid * 8]);
  GLL16(AkS1, &Ak[0][(tid + 512) * 8]);
  #pragma unroll
  for (int j = 0; j < 4; ++j) {
    Vs[0][vl * 129 + vf + j] = ((const float*)&pv0)[j];
    Vs[0][vl * 129 + vf + 4 + j] = ((const float*)&pv1)[j];
  }
  __syncthreads();

  for (int ch = 0; ch < 16; ++ch) {
    int cur = ch & 1, nxt = cur ^ 1;
    if (ch < 15) {
      int lo = (ch + 1) * 32;
      pv0 = *(const float4*)(Vb + (size_t)lo * DD);
      pv1 = *(const float4*)(Vb + (size_t)lo * DD + 4);
      GLL16(AkS0 + lo, &Ak[nxt][tid * 8]);
      GLL16(AkS1 + lo, &Ak[nxt][(tid + 512) * 8]);
    }
    s16x8 af[4];
    #pragma unroll
    for (int mi = 0; mi < 4; ++mi) {
      int m = wm * 64 + mi * 16 + m16;
      af[mi] = *(const s16x8*)&Ak[cur][m * 32 + ((kg ^ keyf(m)) * 8)];
    }
    #pragma unroll
    for (int ni = 0; ni < 4; ++ni) {
      int d = wd * 64 + ni * 16 + m16;
      const float* vs = &Vs[cur][kg * 8 * 129 + d];
      u32x4 bw;
      bw[0] = cvt2(vs[0], vs[129]);
      bw[1] = cvt2(vs[258], vs[387]);
      bw[2] = cvt2(vs[516], vs[645]);
      bw[3] = cvt2(vs[774], vs[903]);
      s16x8 bf = *(s16x8*)&bw;
      #pragma unroll
      for (int mi = 0; mi < 4; ++mi)
        acc[mi][ni] = __builtin_amdgcn_mfma_f32_16x16x32_bf16(af[mi], bf, acc[mi][ni], 0, 0, 0);
    }
    if (ch < 15) {
      #pragma unroll
      for (int j = 0; j < 4; ++j) {
        Vs[nxt][vl * 129 + vf + j] = ((const float*)&pv0)[j];
        Vs[nxt][vl * 129 + vf + 4 + j] = ((const float*)&pv1)[j];
      }
    }
    __syncthreads();
  }

  float* dst = KVp + (((size_t)kc * NB + b) * DD + d0) * MM;
  #pragma unroll
  for (int mi = 0; mi < 4; ++mi)
    #pragma unroll
    for (int ni = 0; ni < 4; ++ni) {
      int d = wd * 64 + ni * 16 + m16;
      int m = wm * 64 + mi * 16 + (kg << 2);
      *(float4*)(dst + (size_t)d * MM + m) = *(float4*)&acc[mi][ni];
    }
}

// ---------------- reduce 8 split-K partials -> KVTf fp32 ----------------
__global__ __launch_bounds__(256) void k_red(const float* __restrict__ KVp, float* __restrict__ KVTf) {
  int i = blockIdx.x * 256 + threadIdx.x;
  const float4* p = (const float4*)KVp;
  float4 s = p[i];
  #pragma unroll
  for (int k = 1; k < 8; ++k) {
    float4 v = p[i + k * 262144];
    s.x += v.x; s.y += v.y; s.z += v.z; s.w += v.w;
  }
  ((float4*)KVTf)[i] = s;
}

// ---------------- out = (rf_q x KVT^T) / (rf_q . Z + eps); KVTf read fp32 ----------------
__global__ __launch_bounds__(512) void k_out(const short* __restrict__ rfq, const float* __restrict__ KVTf,
                                             const float* __restrict__ Zz, float* __restrict__ out) {
  __shared__ short Aq[2][8192];   // [128 l][64 m]
  __shared__ short Bv[2][8192];   // [128 d][64 m]
  __shared__ float zl[256];
  __shared__ float np[512];
  __shared__ float nf[128];
  int l0 = blockIdx.x * 128, d0 = blockIdx.y * 128, b = blockIdx.z;
  int tid = threadIdx.x, lane = tid & 63, w = tid >> 6;
  int wr = w >> 2, wc = w & 3;               // 2(l) x 4(d)
  int brow = tid >> 2, bq = (tid & 3) * 16;
  int bkey = (brow & 7) << 3;
  const float* Kf = KVTf + ((size_t)b * DD + d0 + brow) * MM + bq;
  short* Bw0 = &Bv[0][brow * 64 + (bq ^ bkey)];
  short* Bw1 = &Bv[0][brow * 64 + ((bq + 8) ^ bkey)];
  const short* Ab = rfq + ((size_t)b * LL + l0) * MM;
  int f1 = tid + 512;
  int ar0 = tid >> 3, ac0 = tid & 7, ar1 = f1 >> 3, ac1 = f1 & 7;
  int nrow = tid & 127, nsub = tid >> 7;
  if (tid < 256) zl[tid] = Zz[b * MM + tid];
  fx4 acc[4][2] = {};
  float4 pb[4];
  float na = 0.f;

  #pragma unroll
  for (int i = 0; i < 4; ++i) pb[i] = *(const float4*)(Kf + i * 4);
  GLL16(Ab + (size_t)ar0 * MM + (ac0 ^ (ar0 & 7)) * 8, &Aq[0][tid * 8]);
  GLL16(Ab + (size_t)ar1 * MM + (ac1 ^ (ar1 & 7)) * 8, &Aq[0][f1 * 8]);
  {
    u32x2 v0, v1;
    v0[0] = cvt2(pb[0].x, pb[0].y); v0[1] = cvt2(pb[0].z, pb[0].w);
    v1[0] = cvt2(pb[1].x, pb[1].y); v1[1] = cvt2(pb[1].z, pb[1].w);
    *(u32x2*)Bw0 = v0;
    *(u32x2*)(Bw0 + 4) = v1;
    v0[0] = cvt2(pb[2].x, pb[2].y); v0[1] = cvt2(pb[2].z, pb[2].w);
    v1[0] = cvt2(pb[3].x, pb[3].y); v1[1] = cvt2(pb[3].z, pb[3].w);
    *(u32x2*)Bw1 = v0;
    *(u32x2*)(Bw1 + 4) = v1;
  }
  __syncthreads();

  for (int t = 0; t < 4; ++t) {
    int cur = t & 1, nxt = cur ^ 1;
    int m1 = ((t + 1) & 3) * 64;
    #pragma unroll
    for (int i = 0; i < 4; ++i) pb[i] = *(const float4*)(Kf + m1 + i * 4);
    GLL16(Ab + (size_t)ar0 * MM + m1 + (ac0 ^ (ar0 & 7)) * 8, &Aq[nxt][tid * 8]);
    GLL16(Ab + (size_t)ar1 * MM + m1 + (ac1 ^ (ar1 & 7)) * 8, &Aq[nxt][f1 * 8]);
    #pragma unroll
    for (int kk = 0; kk < 16; ++kk) {
      int k = nsub * 16 + kk;
      na += b2f(Aq[cur][nrow * 64 + (k ^ ((nrow & 7) << 3))]) * zl[t * 64 + k];
    }
    #pragma unroll
    for (int ks = 0; ks < 2; ++ks) {
      int kb = ks * 32 + (lane >> 4) * 8;
      s16x8 af[4], bf[2];
      #pragma unroll
      for (int mi = 0; mi < 4; ++mi) {
        int row = wr * 64 + mi * 16 + (lane & 15);
        af[mi] = *(const s16x8*)&Aq[cur][row * 64 + (kb ^ ((row & 7) << 3))];
      }
      #pragma unroll
      for (int ni = 0; ni < 2; ++ni) {
        int row = wc * 32 + ni * 16 + (lane & 15);
        bf[ni] = *(const s16x8*)&Bv[cur][row * 64 + (kb ^ ((row & 7) << 3))];
      }
      #pragma unroll
      for (int mi = 0; mi < 4; ++mi)
        #pragma unroll
        for (int ni = 0; ni < 2; ++ni)
          acc[mi][ni] = __builtin_amdgcn_mfma_f32_16x16x32_bf16(af[mi], bf[ni], acc[mi][ni], 0, 0, 0);
    }
    {
      u32x2 v0, v1;
      v0[0] = cvt2(pb[0].x, pb[0].y); v0[1] = cvt2(pb[0].z, pb[0].w);
      v1[0] = cvt2(pb[1].x, pb[1].y); v1[1] = cvt2(pb[1].z, pb[1].w);
      *(u32x2*)(Bw0 + nxt * 8192) = v0;
      *(u32x2*)(Bw0 + nxt * 8192 + 4) = v1;
      v0[0] = cvt2(pb[2].x, pb[2].y); v0[1] = cvt2(pb[2].z, pb[2].w);
      v1[0] = cvt2(pb[3].x, pb[3].y); v1[1] = cvt2(pb[3].z, pb[3].w);
      *(u32x2*)(Bw1 + nxt * 8192) = v0;
      *(u32x2*)(Bw1 + nxt * 8192 + 4) = v1;
    }
    __syncthreads();
  }
  np[tid] = na;
  __syncthreads();
  if (tid < 128) nf[tid] = np[tid] + np[tid + 128] + np[tid + 256] + np[tid + 384] + 1e-6f;
  __syncthreads();
  #pragma unroll
  for (int mi = 0; mi < 4; ++mi)
    #pragma unroll
    for (int ni = 0; ni < 2; ++ni) {
      int l = wr * 64 + mi * 16 + ((lane >> 4) << 2);
      int d = d0 + wc * 32 + ni * 16 + (lane & 15);
      #pragma unroll
      for (int u = 0; u < 4; ++u)
        out[((size_t)b * LL + l0 + l + u) * DD + d] = acc[mi][ni][u] / nf[l + u];
    }
}

extern "C" void kernel_launch(void* const* d_in, const int* in_sizes, int n_in,
                              void* d_out, int out_size, void* d_ws, size_t ws_size,
                              hipStream_t stream) {
  const float* Q = (const float*)d_in[0];
  const float* K = (const float*)d_in[1];
  const float* V = (const float*)d_in[2];
  const float* P = (const float*)d_in[3];
  float* out = (float*)d_out;
  char* ws = (char*)d_ws;

  short* Pb   = (short*)(ws + 0);          // 256*1024*2    = 512 KB
  float* Zz   = (float*)(ws + 524288);     // 4*256*4       = 4 KB
  float* KVTf = (float*)(ws + 528384);     // 4*1024*256*4  = 4 MB
  short* rfq  = (short*)(ws + 4722688);    // 4*4096*256*2  = 8 MB
  short* rfkT = (short*)(ws + 13111296);   // 4*256*4096*2  = 8 MB
  float* KVp  = (float*)(ws + 21499904);   // 8*4*1024*256*4 = 32 MB

  k_cast<<<256, 256, 0, stream>>>(P, Pb, 65536);
  (void)hipMemsetAsync(Zz, 0, 4096, stream);
  k_qk<<<dim3(2, 32, 2 * NB), 256, 0, stream>>>(Q, K, Pb, rfq, rfkT, Zz);
  k_kv<<<dim3(8, 8, NB), 512, 0, stream>>>(V, rfkT, KVp);
  k_red<<<1024, 256, 0, stream>>>(KVp, KVTf);
  k_out<<<dim3(32, 8, NB), 512, 0, stream>>>(rfq, KVTf, Zz, out);
}

// Round 7
// 137.435 us; speedup vs baseline: 2.5308x; 1.1108x over previous
//
#include <hip/hip_runtime.h>
#include <math.h>

#define NB 4
#define LL 4096
#define DD 1024
#define MM 256

typedef short s16x8 __attribute__((ext_vector_type(8)));
typedef short s16x4 __attribute__((ext_vector_type(4)));
typedef float fx4 __attribute__((ext_vector_type(4)));
typedef unsigned u32x2 __attribute__((ext_vector_type(2)));
typedef unsigned u32x4 __attribute__((ext_vector_type(4)));

__device__ __forceinline__ float b2f(short s) {
  union { unsigned u; float f; } v;
  v.u = ((unsigned)(unsigned short)s) << 16;
  return v.f;
}
__device__ __forceinline__ short f2b(float f) {
  union { float f; unsigned u; } v;
  v.f = f;
  unsigned r = (v.u + 0x7fffu + ((v.u >> 16) & 1u)) >> 16;
  return (short)(unsigned short)r;
}
// packed fp32->bf16 (RNE), 2 values per instruction
__device__ __forceinline__ unsigned cvt2(float lo, float hi) {
  unsigned r;
  asm("v_cvt_pk_bf16_f32 %0, %1, %2" : "=v"(r) : "v"(lo), "v"(hi));
  return r;
}
// 64-elem (128B) rows, XOR swizzle on 8-elem granule
__device__ __forceinline__ int swz(int row, int col) {
  return row * 64 + (col ^ ((row & 7) << 3));
}
// 4-chunk swizzle key for 32-k-wide GLL16 tiles
__device__ __forceinline__ int keyf(int m) { return (m ^ (m >> 2)) & 3; }

typedef __attribute__((address_space(1))) const void* gas1_t;
typedef __attribute__((address_space(3))) void* las3_t;
#define GLL16(g, l) __builtin_amdgcn_global_load_lds((gas1_t)(const void*)(g), (las3_t)(void*)(l), 16, 0, 0)

// ---------------- cast fp32 -> bf16 (P only) ----------------
__global__ __launch_bounds__(256) void k_cast(const float* __restrict__ in, short* __restrict__ out, int n4) {
  int i = blockIdx.x * 256 + threadIdx.x;
  if (i >= n4) return;
  float4 v = ((const float4*)in)[i];
  s16x4 s;
  s[0] = f2b(v.x); s[1] = f2b(v.y); s[2] = f2b(v.z); s[3] = f2b(v.w);
  ((s16x4*)out)[i] = s;
}

// ---------------- rf GEMM: 64l x 256m (FULL M -> A read once), BK=64, 256 thr, 4 waves, dbuf ----------------
// z<4: rf_q (B,L,M) incl 1/sqrt(M); z>=4: rf_kT (B,M,L) + Z atomics.
__global__ __launch_bounds__(256, 2) void k_qk(const float* __restrict__ Q, const float* __restrict__ K,
                                               const short* __restrict__ Pb,
                                               short* __restrict__ rfq, short* __restrict__ rfkT,
                                               float* __restrict__ Zz) {
  __shared__ short As[2][4096];    // [64 l][64 k] bf16 swz, 8KB x2
  __shared__ short Bs[2][16384];   // [256 m][64 k] bf16 swz, 32KB x2
  int z = blockIdx.z, mode = z >> 2, b = z & 3;
  int l0 = blockIdx.x * 64;
  const float* X = mode ? K : Q;
  int tid = threadIdx.x, lane = tid & 63, w = tid >> 6;   // wave grid 1(l) x 4(m)
  int m16 = lane & 15, kg = lane >> 4;

  // A staging: row = tid>>2 (64 rows), 16 contiguous k per thread
  int arow = tid >> 2, acol = (tid & 3) * 16;
  int akey = (arow & 7) << 3;
  const float* Xr = X + ((size_t)b * LL + l0 + arow) * DD + acol;

  fx4 acc[4][4] = {};
  float4 pa[4];

  // prologue: tile 0
  #pragma unroll
  for (int i = 0; i < 4; ++i) pa[i] = *(const float4*)(Xr + i * 4);
  #pragma unroll
  for (int j = 0; j < 8; ++j) {
    int fl = tid + j * 256, row = fl >> 3, c8 = fl & 7;
    GLL16(Pb + (size_t)row * DD + (c8 ^ (row & 7)) * 8, &Bs[0][fl * 8]);
  }
  {
    u32x4 v0;
    v0[0] = cvt2(pa[0].x, pa[0].y); v0[1] = cvt2(pa[0].z, pa[0].w);
    v0[2] = cvt2(pa[1].x, pa[1].y); v0[3] = cvt2(pa[1].z, pa[1].w);
    *(u32x4*)&As[0][arow * 64 + (acol ^ akey)] = v0;
    v0[0] = cvt2(pa[2].x, pa[2].y); v0[1] = cvt2(pa[2].z, pa[2].w);
    v0[2] = cvt2(pa[3].x, pa[3].y); v0[3] = cvt2(pa[3].z, pa[3].w);
    *(u32x4*)&As[0][arow * 64 + ((acol + 8) ^ akey)] = v0;
  }
  __syncthreads();

  for (int t = 0; t < 16; ++t) {
    int cur = t & 1, nxt = cur ^ 1;
    if (t < 15) {
      int d1 = (t + 1) * 64;
      #pragma unroll
      for (int i = 0; i < 4; ++i) pa[i] = *(const float4*)(Xr + d1 + i * 4);
      #pragma unroll
      for (int j = 0; j < 8; ++j) {
        int fl = tid + j * 256, row = fl >> 3, c8 = fl & 7;
        GLL16(Pb + (size_t)row * DD + d1 + (c8 ^ (row & 7)) * 8, &Bs[nxt][fl * 8]);
      }
    }
    #pragma unroll
    for (int ks = 0; ks < 2; ++ks) {
      int kb = ks * 32 + kg * 8;
      s16x8 af[4], bf[4];
      #pragma unroll
      for (int mi = 0; mi < 4; ++mi) af[mi] = *(const s16x8*)&As[cur][swz(mi * 16 + m16, kb)];
      #pragma unroll
      for (int ni = 0; ni < 4; ++ni) bf[ni] = *(const s16x8*)&Bs[cur][swz(w * 64 + ni * 16 + m16, kb)];
      #pragma unroll
      for (int mi = 0; mi < 4; ++mi)
        #pragma unroll
        for (int ni = 0; ni < 4; ++ni)
          acc[mi][ni] = __builtin_amdgcn_mfma_f32_16x16x32_bf16(af[mi], bf[ni], acc[mi][ni], 0, 0, 0);
    }
    if (t < 15) {
      u32x4 v0;
      v0[0] = cvt2(pa[0].x, pa[0].y); v0[1] = cvt2(pa[0].z, pa[0].w);
      v0[2] = cvt2(pa[1].x, pa[1].y); v0[3] = cvt2(pa[1].z, pa[1].w);
      *(u32x4*)&As[nxt][arow * 64 + (acol ^ akey)] = v0;
      v0[0] = cvt2(pa[2].x, pa[2].y); v0[1] = cvt2(pa[2].z, pa[2].w);
      v0[2] = cvt2(pa[3].x, pa[3].y); v0[3] = cvt2(pa[3].z, pa[3].w);
      *(u32x4*)&As[nxt][arow * 64 + ((acol + 8) ^ akey)] = v0;
    }
    __syncthreads();
  }

  if (mode == 0) {
    #pragma unroll
    for (int mi = 0; mi < 4; ++mi)
      #pragma unroll
      for (int ni = 0; ni < 4; ++ni) {
        int r0 = mi * 16 + (kg << 2);
        int c = w * 64 + ni * 16 + m16;
        #pragma unroll
        for (int u = 0; u < 4; ++u)
          rfq[((size_t)b * LL + l0 + r0 + u) * MM + c] = f2b(expf(acc[mi][ni][u] * 0.03125f) * 0.0625f);
      }
  } else {
    // bounce C^T into Bs overlay [256 m][64 l] (32 KB), fused Z partials
    short* T = (short*)Bs;
    float zp[4] = {0.f, 0.f, 0.f, 0.f};
    #pragma unroll
    for (int mi = 0; mi < 4; ++mi)
      #pragma unroll
      for (int ni = 0; ni < 4; ++ni) {
        int l = mi * 16 + (kg << 2);
        int m = w * 64 + ni * 16 + m16;
        int key = (m & 7) << 3;
        float e0 = expf(acc[mi][ni][0] * 0.03125f);
        float e1 = expf(acc[mi][ni][1] * 0.03125f);
        float e2 = expf(acc[mi][ni][2] * 0.03125f);
        float e3 = expf(acc[mi][ni][3] * 0.03125f);
        zp[ni] += e0 + e1 + e2 + e3;
        *(unsigned*)&T[m * 64 + (l ^ key)] = cvt2(e0, e1);
        *(unsigned*)&T[m * 64 + ((l ^ key) + 2)] = cvt2(e2, e3);
      }
    #pragma unroll
    for (int ni = 0; ni < 4; ++ni) {
      zp[ni] += __shfl_xor(zp[ni], 16);
      zp[ni] += __shfl_xor(zp[ni], 32);
    }
    if (kg == 0) {
      #pragma unroll
      for (int ni = 0; ni < 4; ++ni)
        atomicAdd(&Zz[b * MM + w * 64 + ni * 16 + m16], zp[ni]);
    }
    __syncthreads();
    int m = tid, mkey = (m & 7) << 3;
    short* dst = rfkT + ((size_t)b * MM + m) * LL + l0;
    #pragma unroll
    for (int j = 0; j < 8; ++j) {
      s16x8 v = *(const s16x8*)&T[m * 64 + ((j * 8) ^ mkey)];
      *(s16x8*)(dst + j * 8) = v;
    }
  }
}

// ---------------- KV partials: KVp[kc][b][d][m] = sum over 512 l; NO atomics ----------------
__global__ __launch_bounds__(512) void k_kv(const float* __restrict__ V, const short* __restrict__ rfkT,
                                            float* __restrict__ KVp) {
  __shared__ float Vs[2][32 * 129];   // fp32 [32 l][129 d-pitch] (odd pitch: conflict-free col reads)
  __shared__ short Ak[2][256 * 32];   // rfkT [256 m][32 l] bf16, 4-chunk swizzled
  int d0 = blockIdx.x * 128, kc = blockIdx.y, b = blockIdx.z;
  int ls = kc * 512;
  int tid = threadIdx.x, lane = tid & 63, w = tid >> 6;
  int wm = w >> 1, wd = w & 1;     // 4(m) x 2(d)
  int m16 = lane & 15, kg = lane >> 4;

  int vl = tid >> 4, vf = (tid & 15) * 8;
  const float* Vb = V + ((size_t)b * LL + ls + vl) * DD + d0 + vf;

  int am = tid >> 2, as = tid & 3;
  int acs = as ^ keyf(am);
  const short* AkS0 = rfkT + ((size_t)b * MM + am) * LL + ls + acs * 8;
  const short* AkS1 = rfkT + ((size_t)b * MM + am + 128) * LL + ls + acs * 8;

  fx4 acc[4][4] = {};
  float4 pv0, pv1;

  pv0 = *(const float4*)(Vb);
  pv1 = *(const float4*)(Vb + 4);
  GLL16(AkS0, &Ak[0][tid * 8]);
  GLL16(AkS1, &Ak[0][(tid + 512) * 8]);
  #pragma unroll
  for (int j = 0; j < 4; ++j) {
    Vs[0][vl * 129 + vf + j] = ((const float*)&pv0)[j];
    Vs[0][vl * 129 + vf + 4 + j] = ((const float*)&pv1)[j];
  }
  __syncthreads();

  for (int ch = 0; ch < 16; ++ch) {
    int cur = ch & 1, nxt = cur ^ 1;
    if (ch < 15) {
      int lo = (ch + 1) * 32;
      pv0 = *(const float4*)(Vb + (size_t)lo * DD);
      pv1 = *(const float4*)(Vb + (size_t)lo * DD + 4);
      GLL16(AkS0 + lo, &Ak[nxt][tid * 8]);
      GLL16(AkS1 + lo, &Ak[nxt][(tid + 512) * 8]);
    }
    s16x8 af[4];
    #pragma unroll
    for (int mi = 0; mi < 4; ++mi) {
      int m = wm * 64 + mi * 16 + m16;
      af[mi] = *(const s16x8*)&Ak[cur][m * 32 + ((kg ^ keyf(m)) * 8)];
    }
    #pragma unroll
    for (int ni = 0; ni < 4; ++ni) {
      int d = wd * 64 + ni * 16 + m16;
      const float* vs = &Vs[cur][kg * 8 * 129 + d];
      u32x4 bw;
      bw[0] = cvt2(vs[0], vs[129]);
      bw[1] = cvt2(vs[258], vs[387]);
      bw[2] = cvt2(vs[516], vs[645]);
      bw[3] = cvt2(vs[774], vs[903]);
      s16x8 bf = *(s16x8*)&bw;
      #pragma unroll
      for (int mi = 0; mi < 4; ++mi)
        acc[mi][ni] = __builtin_amdgcn_mfma_f32_16x16x32_bf16(af[mi], bf, acc[mi][ni], 0, 0, 0);
    }
    if (ch < 15) {
      #pragma unroll
      for (int j = 0; j < 4; ++j) {
        Vs[nxt][vl * 129 + vf + j] = ((const float*)&pv0)[j];
        Vs[nxt][vl * 129 + vf + 4 + j] = ((const float*)&pv1)[j];
      }
    }
    __syncthreads();
  }

  float* dst = KVp + (((size_t)kc * NB + b) * DD + d0) * MM;
  #pragma unroll
  for (int mi = 0; mi < 4; ++mi)
    #pragma unroll
    for (int ni = 0; ni < 4; ++ni) {
      int d = wd * 64 + ni * 16 + m16;
      int m = wm * 64 + mi * 16 + (kg << 2);
      *(float4*)(dst + (size_t)d * MM + m) = *(float4*)&acc[mi][ni];
    }
}

// ---------------- reduce 8 split-K partials -> KVTf fp32 ----------------
__global__ __launch_bounds__(256) void k_red(const float* __restrict__ KVp, float* __restrict__ KVTf) {
  int i = blockIdx.x * 256 + threadIdx.x;
  const float4* p = (const float4*)KVp;
  float4 s = p[i];
  #pragma unroll
  for (int k = 1; k < 8; ++k) {
    float4 v = p[i + k * 262144];
    s.x += v.x; s.y += v.y; s.z += v.z; s.w += v.w;
  }
  ((float4*)KVTf)[i] = s;
}

// ---------------- out = (rf_q x KVT^T) / (rf_q . Z + eps); KVTf read fp32 ----------------
__global__ __launch_bounds__(512) void k_out(const short* __restrict__ rfq, const float* __restrict__ KVTf,
                                             const float* __restrict__ Zz, float* __restrict__ out) {
  __shared__ short Aq[2][8192];   // [128 l][64 m]
  __shared__ short Bv[2][8192];   // [128 d][64 m]
  __shared__ float zl[256];
  __shared__ float np[512];
  __shared__ float nf[128];
  int l0 = blockIdx.x * 128, d0 = blockIdx.y * 128, b = blockIdx.z;
  int tid = threadIdx.x, lane = tid & 63, w = tid >> 6;
  int wr = w >> 2, wc = w & 3;               // 2(l) x 4(d)
  int brow = tid >> 2, bq = (tid & 3) * 16;
  int bkey = (brow & 7) << 3;
  const float* Kf = KVTf + ((size_t)b * DD + d0 + brow) * MM + bq;
  short* Bw0 = &Bv[0][brow * 64 + (bq ^ bkey)];
  short* Bw1 = &Bv[0][brow * 64 + ((bq + 8) ^ bkey)];
  const short* Ab = rfq + ((size_t)b * LL + l0) * MM;
  int f1 = tid + 512;
  int ar0 = tid >> 3, ac0 = tid & 7, ar1 = f1 >> 3, ac1 = f1 & 7;
  int nrow = tid & 127, nsub = tid >> 7;
  if (tid < 256) zl[tid] = Zz[b * MM + tid];
  fx4 acc[4][2] = {};
  float4 pb[4];
  float na = 0.f;

  #pragma unroll
  for (int i = 0; i < 4; ++i) pb[i] = *(const float4*)(Kf + i * 4);
  GLL16(Ab + (size_t)ar0 * MM + (ac0 ^ (ar0 & 7)) * 8, &Aq[0][tid * 8]);
  GLL16(Ab + (size_t)ar1 * MM + (ac1 ^ (ar1 & 7)) * 8, &Aq[0][f1 * 8]);
  {
    u32x2 v0, v1;
    v0[0] = cvt2(pb[0].x, pb[0].y); v0[1] = cvt2(pb[0].z, pb[0].w);
    v1[0] = cvt2(pb[1].x, pb[1].y); v1[1] = cvt2(pb[1].z, pb[1].w);
    *(u32x2*)Bw0 = v0;
    *(u32x2*)(Bw0 + 4) = v1;
    v0[0] = cvt2(pb[2].x, pb[2].y); v0[1] = cvt2(pb[2].z, pb[2].w);
    v1[0] = cvt2(pb[3].x, pb[3].y); v1[1] = cvt2(pb[3].z, pb[3].w);
    *(u32x2*)Bw1 = v0;
    *(u32x2*)(Bw1 + 4) = v1;
  }
  __syncthreads();

  for (int t = 0; t < 4; ++t) {
    int cur = t & 1, nxt = cur ^ 1;
    int m1 = ((t + 1) & 3) * 64;
    #pragma unroll
    for (int i = 0; i < 4; ++i) pb[i] = *(const float4*)(Kf + m1 + i * 4);
    GLL16(Ab + (size_t)ar0 * MM + m1 + (ac0 ^ (ar0 & 7)) * 8, &Aq[nxt][tid * 8]);
    GLL16(Ab + (size_t)ar1 * MM + m1 + (ac1 ^ (ar1 & 7)) * 8, &Aq[nxt][f1 * 8]);
    #pragma unroll
    for (int kk = 0; kk < 16; ++kk) {
      int k = nsub * 16 + kk;
      na += b2f(Aq[cur][nrow * 64 + (k ^ ((nrow & 7) << 3))]) * zl[t * 64 + k];
    }
    #pragma unroll
    for (int ks = 0; ks < 2; ++ks) {
      int kb = ks * 32 + (lane >> 4) * 8;
      s16x8 af[4], bf[2];
      #pragma unroll
      for (int mi = 0; mi < 4; ++mi) {
        int row = wr * 64 + mi * 16 + (lane & 15);
        af[mi] = *(const s16x8*)&Aq[cur][row * 64 + (kb ^ ((row & 7) << 3))];
      }
      #pragma unroll
      for (int ni = 0; ni < 2; ++ni) {
        int row = wc * 32 + ni * 16 + (lane & 15);
        bf[ni] = *(const s16x8*)&Bv[cur][row * 64 + (kb ^ ((row & 7) << 3))];
      }
      #pragma unroll
      for (int mi = 0; mi < 4; ++mi)
        #pragma unroll
        for (int ni = 0; ni < 2; ++ni)
          acc[mi][ni] = __builtin_amdgcn_mfma_f32_16x16x32_bf16(af[mi], bf[ni], acc[mi][ni], 0, 0, 0);
    }
    {
      u32x2 v0, v1;
      v0[0] = cvt2(pb[0].x, pb[0].y); v0[1] = cvt2(pb[0].z, pb[0].w);
      v1[0] = cvt2(pb[1].x, pb[1].y); v1[1] = cvt2(pb[1].z, pb[1].w);
      *(u32x2*)(Bw0 + nxt * 8192) = v0;
      *(u32x2*)(Bw0 + nxt * 8192 + 4) = v1;
      v0[0] = cvt2(pb[2].x, pb[2].y); v0[1] = cvt2(pb[2].z, pb[2].w);
      v1[0] = cvt2(pb[3].x, pb[3].y); v1[1] = cvt2(pb[3].z, pb[3].w);
      *(u32x2*)(Bw1 + nxt * 8192) = v0;
      *(u32x2*)(Bw1 + nxt * 8192 + 4) = v1;
    }
    __syncthreads();
  }
  np[tid] = na;
  __syncthreads();
  if (tid < 128) nf[tid] = np[tid] + np[tid + 128] + np[tid + 256] + np[tid + 384] + 1e-6f;
  __syncthreads();
  #pragma unroll
  for (int mi = 0; mi < 4; ++mi)
    #pragma unroll
    for (int ni = 0; ni < 2; ++ni) {
      int l = wr * 64 + mi * 16 + ((lane >> 4) << 2);
      int d = d0 + wc * 32 + ni * 16 + (lane & 15);
      #pragma unroll
      for (int u = 0; u < 4; ++u)
        out[((size_t)b * LL + l0 + l + u) * DD + d] = acc[mi][ni][u] / nf[l + u];
    }
}

extern "C" void kernel_launch(void* const* d_in, const int* in_sizes, int n_in,
                              void* d_out, int out_size, void* d_ws, size_t ws_size,
                              hipStream_t stream) {
  const float* Q = (const float*)d_in[0];
  const float* K = (const float*)d_in[1];
  const float* V = (const float*)d_in[2];
  const float* P = (const float*)d_in[3];
  float* out = (float*)d_out;
  char* ws = (char*)d_ws;

  short* Pb   = (short*)(ws + 0);          // 256*1024*2    = 512 KB
  float* Zz   = (float*)(ws + 524288);     // 4*256*4       = 4 KB
  float* KVTf = (float*)(ws + 528384);     // 4*1024*256*4  = 4 MB
  short* rfq  = (short*)(ws + 4722688);    // 4*4096*256*2  = 8 MB
  short* rfkT = (short*)(ws + 13111296);   // 4*256*4096*2  = 8 MB
  float* KVp  = (float*)(ws + 21499904);   // 8*4*1024*256*4 = 32 MB

  k_cast<<<256, 256, 0, stream>>>(P, Pb, 65536);
  (void)hipMemsetAsync(Zz, 0, 4096, stream);
  k_qk<<<dim3(64, 1, 2 * NB), 256, 0, stream>>>(Q, K, Pb, rfq, rfkT, Zz);
  k_kv<<<dim3(8, 8, NB), 512, 0, stream>>>(V, rfkT, KVp);
  k_red<<<1024, 256, 0, stream>>>(KVp, KVTf);
  k_out<<<dim3(32, 8, NB), 512, 0, stream>>>(rfq, KVTf, Zz, out);
}